// Round 2
// baseline (1172.092 us; speedup 1.0000x reference)
//
#include <hip/hip_runtime.h>
#include <math.h>

#define NSEQ   4096
#define DMODEL 640
#define NHEAD  8
#define DHEAD  64
#define INNER  512   // NHEAD*DHEAD

// ---------------------------------------------------------------------------
// QKV projection. out_z[h][n][d] = sum_c x[n][c] * W_z[c][h*64+d]
// BM=BN=64, BK=16, 256 threads, 4x4 micro-tile per thread.
// blockIdx.z selects {Q,K,V}. Output is head-major [h][N][64].
// ---------------------------------------------------------------------------
__global__ __launch_bounds__(256) void qkv_gemm(
    const float* __restrict__ x,
    const float* __restrict__ Wq, const float* __restrict__ Wk,
    const float* __restrict__ Wv,
    float* __restrict__ qo, float* __restrict__ ko, float* __restrict__ vo)
{
    __shared__ float As[16][68];   // [k][m], padded: all compute reads <=2-way
    __shared__ float Bs[16][64];   // [k][n]
    const int bx = blockIdx.x;               // col tile == head (0..7)
    const int by = blockIdx.y;               // row tile (0..63)
    const int bz = blockIdx.z;               // 0=Q 1=K 2=V
    const float* W = (bz == 0) ? Wq : (bz == 1) ? Wk : Wv;
    float* out     = (bz == 0) ? qo : (bz == 1) ? ko : vo;

    const int tid = threadIdx.x;
    const int tx = tid & 15, ty = tid >> 4;
    const int row0 = by * 64, col0 = bx * 64;

    const int am = tid >> 2;                 // A-load row 0..63
    const int ak = (tid & 3) * 4;            // A-load k 0/4/8/12
    const int bk = tid >> 4;                 // B-load k 0..15
    const int bn = (tid & 15) * 4;           // B-load col

    float acc[4][4] = {};

    for (int k0 = 0; k0 < DMODEL; k0 += 16) {
        float4 av = *(const float4*)&x[(size_t)(row0 + am) * DMODEL + k0 + ak];
        As[ak + 0][am] = av.x;
        As[ak + 1][am] = av.y;
        As[ak + 2][am] = av.z;
        As[ak + 3][am] = av.w;
        *(float4*)&Bs[bk][bn] =
            *(const float4*)&W[(size_t)(k0 + bk) * INNER + col0 + bn];
        __syncthreads();
#pragma unroll
        for (int kk = 0; kk < 16; ++kk) {
            float4 a4 = *(const float4*)&As[kk][ty * 4];
            float4 b4 = *(const float4*)&Bs[kk][tx * 4];
            float a[4] = {a4.x, a4.y, a4.z, a4.w};
            float b[4] = {b4.x, b4.y, b4.z, b4.w};
#pragma unroll
            for (int i = 0; i < 4; ++i)
#pragma unroll
                for (int j = 0; j < 4; ++j)
                    acc[i][j] = fmaf(a[i], b[j], acc[i][j]);
        }
        __syncthreads();
    }

    float* ob = out + (size_t)bx * NSEQ * DHEAD;   // head-major base
#pragma unroll
    for (int i = 0; i < 4; ++i) {
        float4 o = make_float4(acc[i][0], acc[i][1], acc[i][2], acc[i][3]);
        *(float4*)&ob[(size_t)(row0 + ty * 4 + i) * DHEAD + tx * 4] = o;
    }
}

// ---------------------------------------------------------------------------
// Flash attention, fp32. One block = one (head, 64-query tile).
// K tile staged in LDS; V staged via registers, transposed into the SAME
// LDS buffer after QK^T reads complete (keeps LDS at 54KB).
// Online softmax with per-row running max/denominator.
// ---------------------------------------------------------------------------
__global__ __launch_bounds__(256) void attn_fwd(
    const float* __restrict__ q, const float* __restrict__ k,
    const float* __restrict__ v, float* __restrict__ ao)
{
    __shared__ float Qs[64][68];    // Q tile (pre-scaled)
    __shared__ float KVs[64][68];   // K tile, later overwritten with V^T
    __shared__ float Ss[64][68];    // scores, then P=exp(S-m)
    __shared__ float mrow[64], lrow[64], arow[64];
    __shared__ float red[64][4];

    const int qb  = blockIdx.x;     // 0..63 query tile
    const int h   = blockIdx.y;     // 0..7 head
    const int tid = threadIdx.x;
    const int tx = tid & 15, ty = tid >> 4;

    const float* qh = q + (size_t)h * NSEQ * DHEAD;
    const float* kh = k + (size_t)h * NSEQ * DHEAD;
    const float* vh = v + (size_t)h * NSEQ * DHEAD;

#pragma unroll
    for (int r = 0; r < 4; ++r) {
        int idx = tid + r * 256;
        int row = idx >> 4, slot = idx & 15;
        float4 qv = *(const float4*)&qh[(size_t)(qb * 64 + row) * DHEAD + slot * 4];
        qv.x *= 0.125f; qv.y *= 0.125f; qv.z *= 0.125f; qv.w *= 0.125f;
        *(float4*)&Qs[row][slot * 4] = qv;
    }
    if (tid < 64) { mrow[tid] = -INFINITY; lrow[tid] = 0.f; }

    float O[4][4] = {};
    __syncthreads();

    for (int kt = 0; kt < 64; ++kt) {
        float4 vv[4];
#pragma unroll
        for (int r = 0; r < 4; ++r) {
            int idx = tid + r * 256;
            int row = idx >> 4, slot = idx & 15;
            *(float4*)&KVs[row][slot * 4] =
                *(const float4*)&kh[(size_t)(kt * 64 + row) * DHEAD + slot * 4];
            vv[r] = *(const float4*)&vh[(size_t)(kt * 64 + row) * DHEAD + slot * 4];
        }
        __syncthreads();                         // (1) K tile ready

        // S = (Q*scale) K^T. Thread owns rows ty*4+i, cols tx+16b.
        float s[4][4] = {};
#pragma unroll
        for (int d4 = 0; d4 < 16; ++d4) {
            float4 qv4[4], kv4[4];
#pragma unroll
            for (int i = 0; i < 4; ++i)
                qv4[i] = *(const float4*)&Qs[ty * 4 + i][d4 * 4];
#pragma unroll
            for (int b = 0; b < 4; ++b)
                kv4[b] = *(const float4*)&KVs[tx + 16 * b][d4 * 4];
#pragma unroll
            for (int i = 0; i < 4; ++i)
#pragma unroll
                for (int b = 0; b < 4; ++b)
                    s[i][b] += qv4[i].x * kv4[b].x + qv4[i].y * kv4[b].y +
                               qv4[i].z * kv4[b].z + qv4[i].w * kv4[b].w;
        }
#pragma unroll
        for (int i = 0; i < 4; ++i)
#pragma unroll
            for (int b = 0; b < 4; ++b)
                Ss[ty * 4 + i][tx + 16 * b] = s[i][b];
        __syncthreads();                         // (2) Ss ready, K reads done

        // Overwrite KVs with V^T (K no longer needed).
#pragma unroll
        for (int r = 0; r < 4; ++r) {
            int idx = tid + r * 256;
            int row = idx >> 4, slot = idx & 15;
            KVs[slot * 4 + 0][row] = vv[r].x;
            KVs[slot * 4 + 1][row] = vv[r].y;
            KVs[slot * 4 + 2][row] = vv[r].z;
            KVs[slot * 4 + 3][row] = vv[r].w;
        }
        // Partial row-max (4 threads per row).
        {
            int rr = tid >> 2, qq = tid & 3;
            float mx = -INFINITY;
#pragma unroll
            for (int j4 = 0; j4 < 4; ++j4) {
                float4 sv = *(const float4*)&Ss[rr][qq * 16 + j4 * 4];
                mx = fmaxf(mx, fmaxf(fmaxf(sv.x, sv.y), fmaxf(sv.z, sv.w)));
            }
            red[rr][qq] = mx;
        }
        __syncthreads();                         // (3) red + V^T ready

        if (tid < 64) {
            float mx = fmaxf(fmaxf(red[tid][0], red[tid][1]),
                             fmaxf(red[tid][2], red[tid][3]));
            float mo = mrow[tid];
            float mn = fmaxf(mo, mx);
            arow[tid] = __expf(mo - mn);         // exp(-inf)=0 on first tile
            mrow[tid] = mn;
        }
        __syncthreads();                         // (4) m/alpha ready

        // P = exp(S - m), partial row sums.
        {
            int rr = tid >> 2, qq = tid & 3;
            float mn = mrow[rr];
            float sum = 0.f;
#pragma unroll
            for (int j4 = 0; j4 < 4; ++j4) {
                float4 sv = *(const float4*)&Ss[rr][qq * 16 + j4 * 4];
                sv.x = __expf(sv.x - mn); sv.y = __expf(sv.y - mn);
                sv.z = __expf(sv.z - mn); sv.w = __expf(sv.w - mn);
                sum += sv.x + sv.y + sv.z + sv.w;
                *(float4*)&Ss[rr][qq * 16 + j4 * 4] = sv;
            }
            red[rr][qq] = sum;
        }
        __syncthreads();                         // (5) P + partial sums ready

        if (tid < 64)
            lrow[tid] = lrow[tid] * arow[tid] +
                        red[tid][0] + red[tid][1] + red[tid][2] + red[tid][3];

        // O = O*alpha + P @ V. Thread owns rows ty*4+i, out-cols tx+16b.
        {
            float al[4];
#pragma unroll
            for (int i = 0; i < 4; ++i) al[i] = arow[ty * 4 + i];
#pragma unroll
            for (int i = 0; i < 4; ++i)
#pragma unroll
                for (int b = 0; b < 4; ++b) O[i][b] *= al[i];
#pragma unroll
            for (int j4 = 0; j4 < 16; ++j4) {
                float4 p4[4], v4[4];
#pragma unroll
                for (int i = 0; i < 4; ++i)
                    p4[i] = *(const float4*)&Ss[ty * 4 + i][j4 * 4];
#pragma unroll
                for (int b = 0; b < 4; ++b)
                    v4[b] = *(const float4*)&KVs[tx + 16 * b][j4 * 4];
#pragma unroll
                for (int i = 0; i < 4; ++i)
#pragma unroll
                    for (int b = 0; b < 4; ++b)
                        O[i][b] += p4[i].x * v4[b].x + p4[i].y * v4[b].y +
                                   p4[i].z * v4[b].z + p4[i].w * v4[b].w;
            }
        }
        __syncthreads();                         // (6) tile consumed
    }

    // ao[n][h*64+d], n = qb*64 + row
#pragma unroll
    for (int i = 0; i < 4; ++i) {
        float linv = 1.0f / lrow[ty * 4 + i];
#pragma unroll
        for (int b = 0; b < 4; ++b)
            ao[(size_t)(qb * 64 + ty * 4 + i) * INNER + h * DHEAD + tx + 16 * b] =
                O[i][b] * linv;
    }
}

// ---------------------------------------------------------------------------
// Output projection: C[4096][640] = A[4096][512] @ Wo[512][640] + bo
// ---------------------------------------------------------------------------
__global__ __launch_bounds__(256) void out_gemm(
    const float* __restrict__ A,
    const float* __restrict__ W,
    const float* __restrict__ bias,
    float* __restrict__ C)
{
    __shared__ float As[16][68];
    __shared__ float Bs[16][64];
    const int bx = blockIdx.x;               // 0..9
    const int by = blockIdx.y;               // 0..63
    const int tid = threadIdx.x;
    const int tx = tid & 15, ty = tid >> 4;
    const int row0 = by * 64, col0 = bx * 64;
    const int am = tid >> 2, ak = (tid & 3) * 4;
    const int bk = tid >> 4, bn = (tid & 15) * 4;

    float acc[4][4] = {};

    for (int k0 = 0; k0 < INNER; k0 += 16) {
        float4 av = *(const float4*)&A[(size_t)(row0 + am) * INNER + k0 + ak];
        As[ak + 0][am] = av.x;
        As[ak + 1][am] = av.y;
        As[ak + 2][am] = av.z;
        As[ak + 3][am] = av.w;
        *(float4*)&Bs[bk][bn] =
            *(const float4*)&W[(size_t)(k0 + bk) * DMODEL + col0 + bn];
        __syncthreads();
#pragma unroll
        for (int kk = 0; kk < 16; ++kk) {
            float4 a4 = *(const float4*)&As[kk][ty * 4];
            float4 b4 = *(const float4*)&Bs[kk][tx * 4];
            float a[4] = {a4.x, a4.y, a4.z, a4.w};
            float b[4] = {b4.x, b4.y, b4.z, b4.w};
#pragma unroll
            for (int i = 0; i < 4; ++i)
#pragma unroll
                for (int j = 0; j < 4; ++j)
                    acc[i][j] = fmaf(a[i], b[j], acc[i][j]);
        }
        __syncthreads();
    }

#pragma unroll
    for (int i = 0; i < 4; ++i) {
        float4 o;
        o.x = acc[i][0] + bias[col0 + tx * 4 + 0];
        o.y = acc[i][1] + bias[col0 + tx * 4 + 1];
        o.z = acc[i][2] + bias[col0 + tx * 4 + 2];
        o.w = acc[i][3] + bias[col0 + tx * 4 + 3];
        *(float4*)&C[(size_t)(row0 + ty * 4 + i) * DMODEL + col0 + tx * 4] = o;
    }
}

extern "C" void kernel_launch(void* const* d_in, const int* in_sizes, int n_in,
                              void* d_out, int out_size, void* d_ws, size_t ws_size,
                              hipStream_t stream) {
    const float* x  = (const float*)d_in[0];
    const float* Wq = (const float*)d_in[1];
    const float* Wk = (const float*)d_in[2];
    const float* Wv = (const float*)d_in[3];
    const float* Wo = (const float*)d_in[4];
    const float* bo = (const float*)d_in[5];
    float* out = (float*)d_out;

    float* ws = (float*)d_ws;
    const size_t HQ = (size_t)NHEAD * NSEQ * DHEAD;   // 2,097,152 floats
    float* q  = ws;
    float* k  = q + HQ;
    float* v  = k + HQ;
    float* ao = v + HQ;                                // [4096][512]

    qkv_gemm<<<dim3(INNER / 64, NSEQ / 64, 3), 256, 0, stream>>>(
        x, Wq, Wk, Wv, q, k, v);
    attn_fwd<<<dim3(NSEQ / 64, NHEAD), 256, 0, stream>>>(q, k, v, ao);
    out_gemm<<<dim3(DMODEL / 64, NSEQ / 64), 256, 0, stream>>>(ao, Wo, bo, out);
}

// Round 3
// 368.334 us; speedup vs baseline: 3.1821x; 3.1821x over previous
//
#include <hip/hip_runtime.h>
#include <math.h>

#define NSEQ   4096
#define DMODEL 640
#define NHEAD  8
#define DHEAD  64
#define INNER  512   // NHEAD*DHEAD

typedef _Float16 f16;
typedef _Float16 f16x8 __attribute__((ext_vector_type(8)));
typedef float    f32x4 __attribute__((ext_vector_type(4)));
typedef unsigned short u16x8 __attribute__((ext_vector_type(8)));

#define MFMA16(a, b, c) __builtin_amdgcn_mfma_f32_16x16x32_f16((a), (b), (c), 0, 0, 0)

static __device__ inline unsigned short f2h(float x) {
    union { _Float16 h; unsigned short u; } cv;
    cv.h = (_Float16)x;
    return cv.u;
}

// ---------------------------------------------------------------------------
// QKV projection (fp32 compute). Emits f16:
//   q16[h][n][d] (pre-scaled by 1/8), k16[h][n][d], vT16[h][d][n].
// BM=BN=64, BK=16, 256 threads, 4x4 micro-tile. blockIdx.z = {Q,K,V}.
// ---------------------------------------------------------------------------
__global__ __launch_bounds__(256) void qkv_gemm(
    const float* __restrict__ x,
    const float* __restrict__ Wq, const float* __restrict__ Wk,
    const float* __restrict__ Wv,
    unsigned short* __restrict__ qo, unsigned short* __restrict__ ko,
    unsigned short* __restrict__ vo)
{
    __shared__ float As[16][68];
    __shared__ float Bs[16][64];
    const int bx = blockIdx.x;               // head
    const int by = blockIdx.y;               // row tile
    const int bz = blockIdx.z;               // 0=Q 1=K 2=V
    const float* W = (bz == 0) ? Wq : (bz == 1) ? Wk : Wv;

    const int tid = threadIdx.x;
    const int tx = tid & 15, ty = tid >> 4;
    const int row0 = by * 64, col0 = bx * 64;

    const int am = tid >> 2, ak = (tid & 3) * 4;
    const int bk = tid >> 4, bn = (tid & 15) * 4;

    float acc[4][4] = {};

    for (int k0 = 0; k0 < DMODEL; k0 += 16) {
        float4 av = *(const float4*)&x[(size_t)(row0 + am) * DMODEL + k0 + ak];
        As[ak + 0][am] = av.x;
        As[ak + 1][am] = av.y;
        As[ak + 2][am] = av.z;
        As[ak + 3][am] = av.w;
        *(float4*)&Bs[bk][bn] =
            *(const float4*)&W[(size_t)(k0 + bk) * INNER + col0 + bn];
        __syncthreads();
#pragma unroll
        for (int kk = 0; kk < 16; ++kk) {
            float4 a4 = *(const float4*)&As[kk][ty * 4];
            float4 b4 = *(const float4*)&Bs[kk][tx * 4];
            float a[4] = {a4.x, a4.y, a4.z, a4.w};
            float b[4] = {b4.x, b4.y, b4.z, b4.w};
#pragma unroll
            for (int i = 0; i < 4; ++i)
#pragma unroll
                for (int j = 0; j < 4; ++j)
                    acc[i][j] = fmaf(a[i], b[j], acc[i][j]);
        }
        __syncthreads();
    }

    if (bz == 2) {
        // V: store transposed vT[h][d][n], n contiguous (4 rows per store)
        unsigned short* vb = vo + (size_t)bx * DHEAD * NSEQ;
#pragma unroll
        for (int j = 0; j < 4; ++j) {
            ushort4 o;
            o.x = f2h(acc[0][j]); o.y = f2h(acc[1][j]);
            o.z = f2h(acc[2][j]); o.w = f2h(acc[3][j]);
            *(ushort4*)&vb[(size_t)(tx * 4 + j) * NSEQ + row0 + ty * 4] = o;
        }
    } else {
        const float sc = (bz == 0) ? 0.125f : 1.0f;   // fold softmax scale into Q
        unsigned short* ob = ((bz == 0) ? qo : ko) + (size_t)bx * NSEQ * DHEAD;
#pragma unroll
        for (int i = 0; i < 4; ++i) {
            ushort4 o;
            o.x = f2h(acc[i][0] * sc); o.y = f2h(acc[i][1] * sc);
            o.z = f2h(acc[i][2] * sc); o.w = f2h(acc[i][3] * sc);
            *(ushort4*)&ob[(size_t)(row0 + ty * 4 + i) * DHEAD + tx * 4] = o;
        }
    }
}

// ---------------------------------------------------------------------------
// Flash attention with fp16 MFMA (16x16x32), fp32 accumulate + fp32 softmax.
// Block = (head, 64-query tile), 4 waves; wave w owns query strip 16w..16w+15.
// S stays in registers (C-frag row-reduce via shfl_xor within 16-lane group);
// only P (f16) goes through LDS for the PV B-operand. O^T = V^T * P^T.
// LDS: Ks[64][72]f16 + Vt[64][72]f16 (overlaid by Os[64][68]f32) + Ps.
// ---------------------------------------------------------------------------
__global__ __launch_bounds__(256) void attn_fwd(
    const unsigned short* __restrict__ q16,
    const unsigned short* __restrict__ k16,
    const unsigned short* __restrict__ vT16,
    float* __restrict__ ao)
{
    __shared__ __align__(16) unsigned char smem[27648];
    f16 (*Ks)[72] = (f16(*)[72])(smem);              // 9216 B
    f16 (*Vt)[72] = (f16(*)[72])(smem + 9216);       // 9216 B
    f16 (*Ps)[72] = (f16(*)[72])(smem + 18432);      // 9216 B
    float (*Os)[68] = (float(*)[68])(smem);          // 17408 B, overlays Ks+Vt

    const int qb   = blockIdx.x;
    const int h    = blockIdx.y;
    const int tid  = threadIdx.x;
    const int w    = tid >> 6;        // wave 0..3
    const int lane = tid & 63;
    const int lr   = lane & 15;       // fragment row/col index
    const int lc   = lane >> 4;       // k-quarter

    // Q fragments (persistent). q16 is pre-scaled by 1/8.
    const f16* qh = (const f16*)q16 +
                    ((size_t)h * NSEQ + qb * 64 + 16 * w + lr) * DHEAD;
    const f16x8 qf0 = *(const f16x8*)&qh[lc * 8];
    const f16x8 qf1 = *(const f16x8*)&qh[32 + lc * 8];

    float m_run[4], l_run[4];
    f32x4 o[4];
#pragma unroll
    for (int r = 0; r < 4; ++r) {
        m_run[r] = -INFINITY; l_run[r] = 0.f;
        o[r] = (f32x4){0.f, 0.f, 0.f, 0.f};
    }

    // staging indices: thread -> (row, 16-col chunk)
    const int srow = tid >> 2, sc0 = (tid & 3) * 16;
    const f16* kh = (const f16*)k16 + (size_t)h * NSEQ * DHEAD;
    const f16* vh = (const f16*)vT16 + (size_t)h * DHEAD * NSEQ;

    for (int kt = 0; kt < 64; ++kt) {
        // ---- stage K tile [kv][d] and V^T tile [d][kv] (pure copies) ----
        {
            const f16* ksrc = kh + (size_t)(kt * 64 + srow) * DHEAD + sc0;
            *(u16x8*)&Ks[srow][sc0]     = *(const u16x8*)ksrc;
            *(u16x8*)&Ks[srow][sc0 + 8] = *(const u16x8*)(ksrc + 8);
            const f16* vsrc = vh + (size_t)srow * NSEQ + kt * 64 + sc0;
            *(u16x8*)&Vt[srow][sc0]     = *(const u16x8*)vsrc;
            *(u16x8*)&Vt[srow][sc0 + 8] = *(const u16x8*)(vsrc + 8);
        }
        __syncthreads();                               // (1) tiles ready

        // ---- S = Q K^T : 4 col-tiles x (K=64 -> 2 MFMA) ----
        f32x4 s[4];
        const f32x4 zero = {0.f, 0.f, 0.f, 0.f};
#pragma unroll
        for (int t = 0; t < 4; ++t) {
            f16x8 b0 = *(const f16x8*)&Ks[t * 16 + lr][lc * 8];
            f16x8 b1 = *(const f16x8*)&Ks[t * 16 + lr][32 + lc * 8];
            s[t] = MFMA16(qf1, b1, MFMA16(qf0, b0, zero));
        }

        // ---- in-register online softmax ----
        // lane holds rows q' = lc*4 + r (r=0..3), col t*16 + lr
        float pm[4], al[4], p[4][4], ps[4];
#pragma unroll
        for (int r = 0; r < 4; ++r)
            pm[r] = fmaxf(fmaxf(s[0][r], s[1][r]), fmaxf(s[2][r], s[3][r]));
#pragma unroll
        for (int r = 0; r < 4; ++r) {
            pm[r] = fmaxf(pm[r], __shfl_xor(pm[r], 1));
            pm[r] = fmaxf(pm[r], __shfl_xor(pm[r], 2));
            pm[r] = fmaxf(pm[r], __shfl_xor(pm[r], 4));
            pm[r] = fmaxf(pm[r], __shfl_xor(pm[r], 8));
        }
#pragma unroll
        for (int r = 0; r < 4; ++r) {
            float mn = fmaxf(m_run[r], pm[r]);
            al[r] = __expf(m_run[r] - mn);             // 0 on first tile
            m_run[r] = mn;
            ps[r] = 0.f;
        }
#pragma unroll
        for (int t = 0; t < 4; ++t)
#pragma unroll
            for (int r = 0; r < 4; ++r) {
                p[t][r] = __expf(s[t][r] - m_run[r]);
                ps[r] += p[t][r];
            }
#pragma unroll
        for (int r = 0; r < 4; ++r) {
            ps[r] += __shfl_xor(ps[r], 1);
            ps[r] += __shfl_xor(ps[r], 2);
            ps[r] += __shfl_xor(ps[r], 4);
            ps[r] += __shfl_xor(ps[r], 8);
            l_run[r] = l_run[r] * al[r] + ps[r];
        }

        // ---- write P (f16) to LDS, rows = global q-strip rows ----
#pragma unroll
        for (int t = 0; t < 4; ++t)
#pragma unroll
            for (int r = 0; r < 4; ++r)
                Ps[16 * w + lc * 4 + r][t * 16 + lr] = (f16)p[t][r];

        // ---- rescale O by alpha (broadcast alpha from row-basis to col-basis)
        {
            int src = (lr >> 2) << 4;
            float a0 = __shfl(al[0], src), a1 = __shfl(al[1], src);
            float a2 = __shfl(al[2], src), a3 = __shfl(al[3], src);
            int rs = lane & 3;
            float asel = (rs & 2) ? ((rs & 1) ? a3 : a2)
                                  : ((rs & 1) ? a1 : a0);
#pragma unroll
            for (int dt = 0; dt < 4; ++dt) o[dt] *= asel;
        }
        __syncthreads();                               // (2) Ps visible

        // ---- O^T += V^T P^T : 4 d-tiles x (kv=64 -> 2 MFMA) ----
        {
            f16x8 pb0 = *(const f16x8*)&Ps[16 * w + lr][lc * 8];
            f16x8 pb1 = *(const f16x8*)&Ps[16 * w + lr][32 + lc * 8];
#pragma unroll
            for (int dt = 0; dt < 4; ++dt) {
                f16x8 va0 = *(const f16x8*)&Vt[dt * 16 + lr][lc * 8];
                f16x8 va1 = *(const f16x8*)&Vt[dt * 16 + lr][32 + lc * 8];
                o[dt] = MFMA16(va1, pb1, MFMA16(va0, pb0, o[dt]));
            }
        }
        __syncthreads();                               // (3) reads done
    }

    // ---- epilogue: normalize, transpose via LDS, coalesced store ----
    {
        int src = (lr >> 2) << 4;
        float l0 = __shfl(l_run[0], src), l1 = __shfl(l_run[1], src);
        float l2 = __shfl(l_run[2], src), l3 = __shfl(l_run[3], src);
        int rs = lane & 3;
        float lsel = (rs & 2) ? ((rs & 1) ? l3 : l2)
                              : ((rs & 1) ? l1 : l0);
        float linv = 1.0f / lsel;
#pragma unroll
        for (int dt = 0; dt < 4; ++dt)
#pragma unroll
            for (int r = 0; r < 4; ++r)
                Os[dt * 16 + lc * 4 + r][16 * w + lr] = o[dt][r] * linv;
    }
    __syncthreads();
    {
        int qq = tid >> 2, d0 = (tid & 3) * 16;
        size_t nbase = ((size_t)(qb * 64 + qq)) * INNER + h * DHEAD;
#pragma unroll
        for (int i4 = 0; i4 < 4; ++i4) {
            float4 ov;
            ov.x = Os[d0 + 4 * i4 + 0][qq];
            ov.y = Os[d0 + 4 * i4 + 1][qq];
            ov.z = Os[d0 + 4 * i4 + 2][qq];
            ov.w = Os[d0 + 4 * i4 + 3][qq];
            *(float4*)&ao[nbase + d0 + 4 * i4] = ov;
        }
    }
}

// ---------------------------------------------------------------------------
// Output projection: C[4096][640] = A[4096][512] @ Wo[512][640] + bo (fp32)
// ---------------------------------------------------------------------------
__global__ __launch_bounds__(256) void out_gemm(
    const float* __restrict__ A,
    const float* __restrict__ W,
    const float* __restrict__ bias,
    float* __restrict__ C)
{
    __shared__ float As[16][68];
    __shared__ float Bs[16][64];
    const int bx = blockIdx.x;
    const int by = blockIdx.y;
    const int tid = threadIdx.x;
    const int tx = tid & 15, ty = tid >> 4;
    const int row0 = by * 64, col0 = bx * 64;
    const int am = tid >> 2, ak = (tid & 3) * 4;
    const int bk = tid >> 4, bn = (tid & 15) * 4;

    float acc[4][4] = {};

    for (int k0 = 0; k0 < INNER; k0 += 16) {
        float4 av = *(const float4*)&A[(size_t)(row0 + am) * INNER + k0 + ak];
        As[ak + 0][am] = av.x;
        As[ak + 1][am] = av.y;
        As[ak + 2][am] = av.z;
        As[ak + 3][am] = av.w;
        *(float4*)&Bs[bk][bn] =
            *(const float4*)&W[(size_t)(k0 + bk) * DMODEL + col0 + bn];
        __syncthreads();
#pragma unroll
        for (int kk = 0; kk < 16; ++kk) {
            float4 a4 = *(const float4*)&As[kk][ty * 4];
            float4 b4 = *(const float4*)&Bs[kk][tx * 4];
            float a[4] = {a4.x, a4.y, a4.z, a4.w};
            float b[4] = {b4.x, b4.y, b4.z, b4.w};
#pragma unroll
            for (int i = 0; i < 4; ++i)
#pragma unroll
                for (int j = 0; j < 4; ++j)
                    acc[i][j] = fmaf(a[i], b[j], acc[i][j]);
        }
        __syncthreads();
    }

#pragma unroll
    for (int i = 0; i < 4; ++i) {
        float4 o;
        o.x = acc[i][0] + bias[col0 + tx * 4 + 0];
        o.y = acc[i][1] + bias[col0 + tx * 4 + 1];
        o.z = acc[i][2] + bias[col0 + tx * 4 + 2];
        o.w = acc[i][3] + bias[col0 + tx * 4 + 3];
        *(float4*)&C[(size_t)(row0 + ty * 4 + i) * DMODEL + col0 + tx * 4] = o;
    }
}

extern "C" void kernel_launch(void* const* d_in, const int* in_sizes, int n_in,
                              void* d_out, int out_size, void* d_ws, size_t ws_size,
                              hipStream_t stream) {
    const float* x  = (const float*)d_in[0];
    const float* Wq = (const float*)d_in[1];
    const float* Wk = (const float*)d_in[2];
    const float* Wv = (const float*)d_in[3];
    const float* Wo = (const float*)d_in[4];
    const float* bo = (const float*)d_in[5];
    float* out = (float*)d_out;

    const size_t HQ = (size_t)NHEAD * NSEQ * DHEAD;       // 2,097,152 elems
    unsigned short* q16 = (unsigned short*)d_ws;
    unsigned short* k16 = q16 + HQ;
    unsigned short* vT16 = k16 + HQ;
    float* ao = (float*)(vT16 + HQ);                      // [4096][512] fp32

    qkv_gemm<<<dim3(NHEAD, NSEQ / 64, 3), 256, 0, stream>>>(
        x, Wq, Wk, Wv, q16, k16, vT16);
    attn_fwd<<<dim3(NSEQ / 64, NHEAD), 256, 0, stream>>>(q16, k16, vT16, ao);
    out_gemm<<<dim3(DMODEL / 64, NSEQ / 64), 256, 0, stream>>>(ao, Wo, bo, out);
}

// Round 4
// 202.379 us; speedup vs baseline: 5.7916x; 1.8200x over previous
//
#include <hip/hip_runtime.h>
#include <math.h>

#define NSEQ   4096
#define DMODEL 640
#define NHEAD  8
#define DHEAD  64
#define INNER  512   // NHEAD*DHEAD

typedef _Float16 f16;
typedef _Float16 f16x8 __attribute__((ext_vector_type(8)));
typedef _Float16 f16x4 __attribute__((ext_vector_type(4)));
typedef float    f32x4 __attribute__((ext_vector_type(4)));

#define MFMA16(a, b, c) __builtin_amdgcn_mfma_f32_16x16x32_f16((a), (b), (c), 0, 0, 0)

// Q prescale: softmax scale 1/8 folded with log2(e) so softmax uses raw v_exp_f32
#define QSCALE 0.18033688011112042f

// global -> LDS direct copy, 16B per lane, wave-uniform LDS base.
__device__ __forceinline__ void gl16(const f16* g, f16* l) {
    __builtin_amdgcn_global_load_lds(
        (const __attribute__((address_space(1))) unsigned int*)g,
        (__attribute__((address_space(3))) unsigned int*)l, 16, 0, 0);
}

// ---------------------------------------------------------------------------
// Prep: x (f32) -> xh (f16), 8 elems/thread
// ---------------------------------------------------------------------------
__global__ __launch_bounds__(256) void cvt_x(const float* __restrict__ x,
                                             f16* __restrict__ xh) {
    int i = (blockIdx.x * 256 + threadIdx.x) * 8;
    float4 a = *(const float4*)&x[i];
    float4 b = *(const float4*)&x[i + 4];
    f16x8 o = {(f16)a.x, (f16)a.y, (f16)a.z, (f16)a.w,
               (f16)b.x, (f16)b.y, (f16)b.z, (f16)b.w};
    *(f16x8*)&xh[i] = o;
}

// ---------------------------------------------------------------------------
// Prep: transpose+convert  src f32 [R][C] -> dst f16 [C][R].  64x64 tiles.
// ---------------------------------------------------------------------------
__global__ __launch_bounds__(256) void transpose_cvt(
    const float* __restrict__ src, f16* __restrict__ dst, int R, int C) {
    __shared__ __align__(16) f16 T[64][72];
    const int c0 = blockIdx.x * 64, r0 = blockIdx.y * 64;
    const int t = threadIdx.x;
    {
        int r = t >> 2, cb = (t & 3) * 16;
#pragma unroll
        for (int i = 0; i < 16; i += 4) {
            float4 v = *(const float4*)&src[(size_t)(r0 + r) * C + c0 + cb + i];
            T[cb + i + 0][r] = (f16)v.x;
            T[cb + i + 1][r] = (f16)v.y;
            T[cb + i + 2][r] = (f16)v.z;
            T[cb + i + 3][r] = (f16)v.w;
        }
    }
    __syncthreads();
    {
        int c = t >> 2, rb = (t & 3) * 16;
        f16* d = dst + (size_t)(c0 + c) * R + r0 + rb;
        *(f16x8*)d = *(const f16x8*)&T[c][rb];
        *(f16x8*)(d + 8) = *(const f16x8*)&T[c][rb + 8];
    }
}

// ---------------------------------------------------------------------------
// QKV projection, f16 MFMA. C = xh[4096][640] * WT^T, WT = W^T f16 [512][640].
// M-tile 64 (4 waves x 16-row strip), N-tile 64 (== one head), K-step 64.
// LDS tiles swizzled (byte ^= (row&7)<<4) staged via global_load_lds.
// Outputs: z=0 Q (prescaled) [h][n][d], z=1 K [h][n][d], z=2 V^T [h][d][n].
// ---------------------------------------------------------------------------
__global__ __launch_bounds__(256) void qkv_gemm16(
    const f16* __restrict__ xh,
    const f16* __restrict__ WTq, const f16* __restrict__ WTk,
    const f16* __restrict__ WTv,
    f16* __restrict__ q16, f16* __restrict__ k16, f16* __restrict__ vT16)
{
    __shared__ __align__(16) f16 Xs[4096];
    __shared__ __align__(16) f16 Ws[4096];
    __shared__ __align__(16) f16 Cs[64][72];

    const int bx = blockIdx.x;               // head / N-tile
    const int by = blockIdx.y;               // M-tile
    const int bz = blockIdx.z;               // 0=Q 1=K 2=V
    const f16* WT = (bz == 0) ? WTq : (bz == 1) ? WTk : WTv;

    const int tid = threadIdx.x;
    const int w = tid >> 6, lane = tid & 63;
    const int lr = lane & 15, lc = lane >> 4;
    const int srow8 = lane >> 3;             // 0..7
    const int le = 8 * ((lane & 7) ^ srow8); // inverse-swizzled src elem
    const int swz0 = 8 * (lc ^ (lr & 7));    // swizzled read offsets
    const int swz1 = 8 * ((lc + 4) ^ (lr & 7));
    const int m0 = by * 64, n0 = bx * 64;

    f32x4 acc[4] = {};

    for (int s = 0; s < DMODEL / 64; ++s) {
        const int k0 = s * 64;
#pragma unroll
        for (int c = 0; c < 2; ++c) {
            const int cc = w * 2 + c;        // 8 chunks of 1KB each
            gl16(xh + (size_t)(m0 + cc * 8 + srow8) * DMODEL + k0 + le,
                 &Xs[cc * 512]);
            gl16(WT + (size_t)(n0 + cc * 8 + srow8) * DMODEL + k0 + le,
                 &Ws[cc * 512]);
        }
        __syncthreads();
        f16x8 a0 = *(const f16x8*)&Xs[(16 * w + lr) * 64 + swz0];
        f16x8 a1 = *(const f16x8*)&Xs[(16 * w + lr) * 64 + swz1];
#pragma unroll
        for (int nt = 0; nt < 4; ++nt) {
            f16x8 b0 = *(const f16x8*)&Ws[(nt * 16 + lr) * 64 + swz0];
            f16x8 b1 = *(const f16x8*)&Ws[(nt * 16 + lr) * 64 + swz1];
            acc[nt] = MFMA16(a1, b1, MFMA16(a0, b0, acc[nt]));
        }
        __syncthreads();
    }

    // Epilogue via LDS for coalesced f16 stores.
    const float sc = (bz == 0) ? QSCALE : 1.0f;
    if (bz < 2) {
#pragma unroll
        for (int nt = 0; nt < 4; ++nt)
#pragma unroll
            for (int r = 0; r < 4; ++r)
                Cs[16 * w + lc * 4 + r][nt * 16 + lr] = (f16)(acc[nt][r] * sc);
    } else {  // V: store transposed
#pragma unroll
        for (int nt = 0; nt < 4; ++nt)
#pragma unroll
            for (int r = 0; r < 4; ++r)
                Cs[nt * 16 + lr][16 * w + lc * 4 + r] = (f16)acc[nt][r];
    }
    __syncthreads();
    {
        const int rr = tid >> 2, cb = (tid & 3) * 16;
        f16x8 v0 = *(const f16x8*)&Cs[rr][cb];
        f16x8 v1 = *(const f16x8*)&Cs[rr][cb + 8];
        f16* dst;
        if (bz == 0)
            dst = q16 + ((size_t)bx * NSEQ + m0 + rr) * DHEAD + cb;
        else if (bz == 1)
            dst = k16 + ((size_t)bx * NSEQ + m0 + rr) * DHEAD + cb;
        else
            dst = vT16 + ((size_t)bx * DHEAD + rr) * NSEQ + m0 + cb;
        *(f16x8*)dst = v0;
        *(f16x8*)(dst + 8) = v1;
    }
}

// ---------------------------------------------------------------------------
// Flash attention, swapped-operand QK^T (S^T via mfma(K,Q)) so softmax is
// lane-local per q-row: reduce = 2 shfl_xor. 2 waves/block, QBLK=32,
// grid 1024 -> 4 blocks/CU. K/V double-buffered via global_load_lds with
// XOR-swizzled layout; ONE barrier per KV tile. P via per-wave LDS strip.
// ---------------------------------------------------------------------------
__global__ __launch_bounds__(128) void attn_fwd(
    const f16* __restrict__ q16, const f16* __restrict__ k16,
    const f16* __restrict__ vT16, f16* __restrict__ aoh)
{
    __shared__ __align__(16) f16 KsB[2][4096];   // [kv 64][d 64] swizzled
    __shared__ __align__(16) f16 VtB[2][4096];   // [d 64][kv 64] swizzled
    __shared__ __align__(16) f16 Ps[32][72];     // [q-local][kv], per-wave strip

    const int qb = blockIdx.x;       // 0..127  (32 q-rows each)
    const int h  = blockIdx.y;       // 0..7
    const int tid = threadIdx.x;
    const int w = tid >> 6, lane = tid & 63;
    const int lr = lane & 15, lc = lane >> 4;
    const int srow8 = lane >> 3;
    const int le = 8 * ((lane & 7) ^ srow8);
    const int swz0 = 8 * (lc ^ (lr & 7));
    const int swz1 = 8 * ((lc + 4) ^ (lr & 7));

    const f16* kh = k16 + (size_t)h * NSEQ * DHEAD;
    const f16* vh = vT16 + (size_t)h * DHEAD * NSEQ;

    // Q fragments (persistent, prescaled by 0.125*log2e)
    const f16* qp = q16 + ((size_t)h * NSEQ + qb * 32 + 16 * w + lr) * DHEAD;
    const f16x8 qf0 = *(const f16x8*)&qp[lc * 8];
    const f16x8 qf1 = *(const f16x8*)&qp[32 + lc * 8];

    float m_run = -INFINITY, l_run = 0.f;
    f32x4 o[4] = {};

    // stage tile 0 into buffer 0
#pragma unroll
    for (int c = 0; c < 4; ++c) {
        const int cc = w * 4 + c;
        gl16(kh + (size_t)cc * 512 + srow8 * 64 + le, &KsB[0][cc * 512]);
        gl16(vh + ((size_t)(cc * 8 + srow8)) * NSEQ + le, &VtB[0][cc * 512]);
    }
    __syncthreads();

    for (int kt = 0; kt < 64; ++kt) {
        const int cur = kt & 1;
        if (kt < 63) {
            const int nb = cur ^ 1;
#pragma unroll
            for (int c = 0; c < 4; ++c) {
                const int cc = w * 4 + c;
                gl16(kh + (size_t)(kt + 1) * 4096 + cc * 512 + srow8 * 64 + le,
                     &KsB[nb][cc * 512]);
                gl16(vh + ((size_t)(cc * 8 + srow8)) * NSEQ + (kt + 1) * 64 + le,
                     &VtB[nb][cc * 512]);
            }
        }

        // ---- S^T = K Q^T: lane holds S[q = strip lr][k = t*16 + lc*4 + r]
        f32x4 s[4];
        const f32x4 z4 = {0.f, 0.f, 0.f, 0.f};
#pragma unroll
        for (int t = 0; t < 4; ++t) {
            f16x8 ka = *(const f16x8*)&KsB[cur][(t * 16 + lr) * 64 + swz0];
            f16x8 kb = *(const f16x8*)&KsB[cur][(t * 16 + lr) * 64 + swz1];
            s[t] = MFMA16(kb, qf1, MFMA16(ka, qf0, z4));
        }

        // ---- lane-local online softmax (log2 domain)
        float pm = s[0][0];
#pragma unroll
        for (int t = 0; t < 4; ++t)
#pragma unroll
            for (int r = 0; r < 4; ++r) pm = fmaxf(pm, s[t][r]);
        pm = fmaxf(pm, __shfl_xor(pm, 16));
        pm = fmaxf(pm, __shfl_xor(pm, 32));
        const float mn = fmaxf(m_run, pm);
        const float al = __builtin_amdgcn_exp2f(m_run - mn);
        m_run = mn;
        float p[4][4];
        float ps = 0.f;
#pragma unroll
        for (int t = 0; t < 4; ++t)
#pragma unroll
            for (int r = 0; r < 4; ++r) {
                p[t][r] = __builtin_amdgcn_exp2f(s[t][r] - mn);
                ps += p[t][r];
            }
        ps += __shfl_xor(ps, 16);
        ps += __shfl_xor(ps, 32);
        l_run = l_run * al + ps;

        // ---- P -> LDS (own wave strip only), packed b64 writes
#pragma unroll
        for (int t = 0; t < 4; ++t) {
            f16x4 pk = {(f16)p[t][0], (f16)p[t][1], (f16)p[t][2], (f16)p[t][3]};
            *(f16x4*)&Ps[16 * w + lr][t * 16 + lc * 4] = pk;
        }

        // ---- rescale O (alpha lane-local: O^T col = q = lr)
#pragma unroll
        for (int dt = 0; dt < 4; ++dt) o[dt] *= al;

        // ---- O^T += V^T P^T
        f16x8 pb0 = *(const f16x8*)&Ps[16 * w + lr][lc * 8];
        f16x8 pb1 = *(const f16x8*)&Ps[16 * w + lr][32 + lc * 8];
#pragma unroll
        for (int dt = 0; dt < 4; ++dt) {
            f16x8 va0 = *(const f16x8*)&VtB[cur][(dt * 16 + lr) * 64 + swz0];
            f16x8 va1 = *(const f16x8*)&VtB[cur][(dt * 16 + lr) * 64 + swz1];
            o[dt] = MFMA16(va1, pb1, MFMA16(va0, pb0, o[dt]));
        }
        __syncthreads();   // staging(kt+1) complete; buf[cur] reads done
    }

    // ---- epilogue: normalize, f16, direct stores (q = lane-local row)
    const float linv = 1.0f / l_run;
    f16* dst = aoh + ((size_t)(qb * 32 + 16 * w + lr)) * INNER + h * DHEAD;
#pragma unroll
    for (int dt = 0; dt < 4; ++dt) {
        f16x4 ov = {(f16)(o[dt][0] * linv), (f16)(o[dt][1] * linv),
                    (f16)(o[dt][2] * linv), (f16)(o[dt][3] * linv)};
        *(f16x4*)&dst[dt * 16 + lc * 4] = ov;
    }
}

// ---------------------------------------------------------------------------
// Output projection, f16 MFMA: C[4096][640] = aoh[4096][512] * WoT^T + bo
// WoT = Wo^T f16 [640][512]. Direct f32 stores + bias.
// ---------------------------------------------------------------------------
__global__ __launch_bounds__(256) void out_gemm16(
    const f16* __restrict__ A, const f16* __restrict__ WoT,
    const float* __restrict__ bias, float* __restrict__ C)
{
    __shared__ __align__(16) f16 Xs[4096];
    __shared__ __align__(16) f16 Ws[4096];

    const int bx = blockIdx.x;   // N-tile 0..9
    const int by = blockIdx.y;   // M-tile 0..63
    const int tid = threadIdx.x;
    const int w = tid >> 6, lane = tid & 63;
    const int lr = lane & 15, lc = lane >> 4;
    const int srow8 = lane >> 3;
    const int le = 8 * ((lane & 7) ^ srow8);
    const int swz0 = 8 * (lc ^ (lr & 7));
    const int swz1 = 8 * ((lc + 4) ^ (lr & 7));
    const int m0 = by * 64, n0 = bx * 64;

    f32x4 acc[4] = {};

    for (int s = 0; s < INNER / 64; ++s) {
        const int k0 = s * 64;
#pragma unroll
        for (int c = 0; c < 2; ++c) {
            const int cc = w * 2 + c;
            gl16(A + (size_t)(m0 + cc * 8 + srow8) * INNER + k0 + le,
                 &Xs[cc * 512]);
            gl16(WoT + (size_t)(n0 + cc * 8 + srow8) * INNER + k0 + le,
                 &Ws[cc * 512]);
        }
        __syncthreads();
        f16x8 a0 = *(const f16x8*)&Xs[(16 * w + lr) * 64 + swz0];
        f16x8 a1 = *(const f16x8*)&Xs[(16 * w + lr) * 64 + swz1];
#pragma unroll
        for (int nt = 0; nt < 4; ++nt) {
            f16x8 b0 = *(const f16x8*)&Ws[(nt * 16 + lr) * 64 + swz0];
            f16x8 b1 = *(const f16x8*)&Ws[(nt * 16 + lr) * 64 + swz1];
            acc[nt] = MFMA16(a1, b1, MFMA16(a0, b0, acc[nt]));
        }
        __syncthreads();
    }

#pragma unroll
    for (int nt = 0; nt < 4; ++nt) {
        const float b = bias[n0 + nt * 16 + lr];
#pragma unroll
        for (int r = 0; r < 4; ++r)
            C[(size_t)(m0 + 16 * w + lc * 4 + r) * DMODEL + n0 + nt * 16 + lr] =
                acc[nt][r] + b;
    }
}

extern "C" void kernel_launch(void* const* d_in, const int* in_sizes, int n_in,
                              void* d_out, int out_size, void* d_ws, size_t ws_size,
                              hipStream_t stream) {
    const float* x  = (const float*)d_in[0];
    const float* Wq = (const float*)d_in[1];
    const float* Wk = (const float*)d_in[2];
    const float* Wv = (const float*)d_in[3];
    const float* Wo = (const float*)d_in[4];
    const float* bo = (const float*)d_in[5];
    float* out = (float*)d_out;

    // workspace layout (f16 elements)
    f16* xh  = (f16*)d_ws;                       // 4096*640   = 2,621,440
    f16* WTq = xh  + (size_t)NSEQ * DMODEL;      // 512*640    =   327,680
    f16* WTk = WTq + (size_t)INNER * DMODEL;
    f16* WTv = WTk + (size_t)INNER * DMODEL;
    f16* WoT = WTv + (size_t)INNER * DMODEL;     // 640*512
    f16* q16 = WoT + (size_t)DMODEL * INNER;     // 8*4096*64  = 2,097,152
    f16* k16 = q16 + (size_t)NHEAD * NSEQ * DHEAD;
    f16* vT16 = k16 + (size_t)NHEAD * NSEQ * DHEAD;
    f16* aoh  = vT16 + (size_t)NHEAD * NSEQ * DHEAD;  // 4096*512

    cvt_x<<<NSEQ * DMODEL / (256 * 8), 256, 0, stream>>>(x, xh);
    transpose_cvt<<<dim3(INNER / 64, DMODEL / 64), 256, 0, stream>>>(Wq, WTq, DMODEL, INNER);
    transpose_cvt<<<dim3(INNER / 64, DMODEL / 64), 256, 0, stream>>>(Wk, WTk, DMODEL, INNER);
    transpose_cvt<<<dim3(INNER / 64, DMODEL / 64), 256, 0, stream>>>(Wv, WTv, DMODEL, INNER);
    transpose_cvt<<<dim3(DMODEL / 64, INNER / 64), 256, 0, stream>>>(Wo, WoT, INNER, DMODEL);

    qkv_gemm16<<<dim3(NHEAD, NSEQ / 64, 3), 256, 0, stream>>>(
        xh, WTq, WTk, WTv, q16, k16, vT16);
    attn_fwd<<<dim3(NSEQ / 32, NHEAD), 128, 0, stream>>>(q16, k16, vT16, aoh);
    out_gemm16<<<dim3(DMODEL / 64, NSEQ / 64), 256, 0, stream>>>(aoh, WoT, bo, out);
}

// Round 5
// 171.481 us; speedup vs baseline: 6.8351x; 1.1802x over previous
//
#include <hip/hip_runtime.h>
#include <math.h>

#define NSEQ   4096
#define DMODEL 640
#define NHEAD  8
#define DHEAD  64
#define INNER  512   // NHEAD*DHEAD

typedef _Float16 f16;
typedef _Float16 f16x8 __attribute__((ext_vector_type(8)));
typedef _Float16 f16x4 __attribute__((ext_vector_type(4)));
typedef float    f32x4 __attribute__((ext_vector_type(4)));

#define MFMA16(a, b, c) __builtin_amdgcn_mfma_f32_16x16x32_f16((a), (b), (c), 0, 0, 0)

// softmax scale 1/8 folded with log2(e): softmax runs in exp2 domain
#define QSCALE 0.18033688011112042f

// global -> LDS direct copy, 16B/lane, wave-uniform LDS base.
__device__ __forceinline__ void gl16(const f16* g, f16* l) {
    __builtin_amdgcn_global_load_lds(
        (const __attribute__((address_space(1))) unsigned int*)g,
        (__attribute__((address_space(3))) unsigned int*)l, 16, 0, 0);
}

// ---------------------------------------------------------------------------
// Prep: x (f32) -> xh (f16), 8 elems/thread
// ---------------------------------------------------------------------------
__global__ __launch_bounds__(256) void cvt_x(const float* __restrict__ x,
                                             f16* __restrict__ xh) {
    int i = (blockIdx.x * 256 + threadIdx.x) * 8;
    float4 a = *(const float4*)&x[i];
    float4 b = *(const float4*)&x[i + 4];
    f16x8 o = {(f16)a.x, (f16)a.y, (f16)a.z, (f16)a.w,
               (f16)b.x, (f16)b.y, (f16)b.z, (f16)b.w};
    *(f16x8*)&xh[i] = o;
}

// ---------------------------------------------------------------------------
// Prep: transpose+convert Wq/Wk/Wv f32 [640][512] -> f16 [512][640] (one launch)
// ---------------------------------------------------------------------------
__global__ __launch_bounds__(256) void transpose_cvt3(
    const float* __restrict__ Wq, const float* __restrict__ Wk,
    const float* __restrict__ Wv,
    f16* __restrict__ WTq, f16* __restrict__ WTk, f16* __restrict__ WTv) {
    __shared__ __align__(16) f16 T[64][72];
    const float* src = blockIdx.z == 0 ? Wq : blockIdx.z == 1 ? Wk : Wv;
    f16* dst = blockIdx.z == 0 ? WTq : blockIdx.z == 1 ? WTk : WTv;
    const int R = DMODEL, C = INNER;
    const int c0 = blockIdx.x * 64, r0 = blockIdx.y * 64;
    const int t = threadIdx.x;
    {
        int r = t >> 2, cb = (t & 3) * 16;
#pragma unroll
        for (int i = 0; i < 16; i += 4) {
            float4 v = *(const float4*)&src[(size_t)(r0 + r) * C + c0 + cb + i];
            T[cb + i + 0][r] = (f16)v.x;
            T[cb + i + 1][r] = (f16)v.y;
            T[cb + i + 2][r] = (f16)v.z;
            T[cb + i + 3][r] = (f16)v.w;
        }
    }
    __syncthreads();
    {
        int c = t >> 2, rb = (t & 3) * 16;
        f16* d = dst + (size_t)(c0 + c) * R + r0 + rb;
        *(f16x8*)d = *(const f16x8*)&T[c][rb];
        *(f16x8*)(d + 8) = *(const f16x8*)&T[c][rb + 8];
    }
}

// Same for Wo f32 [512][640] -> WoT f16 [640][512]
__global__ __launch_bounds__(256) void transpose_cvt(
    const float* __restrict__ src, f16* __restrict__ dst, int R, int C) {
    __shared__ __align__(16) f16 T[64][72];
    const int c0 = blockIdx.x * 64, r0 = blockIdx.y * 64;
    const int t = threadIdx.x;
    {
        int r = t >> 2, cb = (t & 3) * 16;
#pragma unroll
        for (int i = 0; i < 16; i += 4) {
            float4 v = *(const float4*)&src[(size_t)(r0 + r) * C + c0 + cb + i];
            T[cb + i + 0][r] = (f16)v.x;
            T[cb + i + 1][r] = (f16)v.y;
            T[cb + i + 2][r] = (f16)v.z;
            T[cb + i + 3][r] = (f16)v.w;
        }
    }
    __syncthreads();
    {
        int c = t >> 2, rb = (t & 3) * 16;
        f16* d = dst + (size_t)(c0 + c) * R + r0 + rb;
        *(f16x8*)d = *(const f16x8*)&T[c][rb];
        *(f16x8*)(d + 8) = *(const f16x8*)&T[c][rb + 8];
    }
}

// ---------------------------------------------------------------------------
// QKV projection, f16 MFMA (unchanged structure from round 4).
// Outputs: z=0 Q (prescaled) [h][n][d], z=1 K [h][n][d], z=2 V^T [h][d][n].
// ---------------------------------------------------------------------------
__global__ __launch_bounds__(256) void qkv_gemm16(
    const f16* __restrict__ xh,
    const f16* __restrict__ WTq, const f16* __restrict__ WTk,
    const f16* __restrict__ WTv,
    f16* __restrict__ q16, f16* __restrict__ k16, f16* __restrict__ vT16)
{
    __shared__ __align__(16) f16 Xs[4096];
    __shared__ __align__(16) f16 Ws[4096];
    __shared__ __align__(16) f16 Cs[64][72];

    const int bx = blockIdx.x;               // head / N-tile
    const int by = blockIdx.y;               // M-tile
    const int bz = blockIdx.z;               // 0=Q 1=K 2=V
    const f16* WT = (bz == 0) ? WTq : (bz == 1) ? WTk : WTv;

    const int tid = threadIdx.x;
    const int w = tid >> 6, lane = tid & 63;
    const int lr = lane & 15, lc = lane >> 4;
    const int srow8 = lane >> 3;
    const int le = 8 * ((lane & 7) ^ srow8);
    const int swz0 = 8 * (lc ^ (lr & 7));
    const int swz1 = 8 * ((lc + 4) ^ (lr & 7));
    const int m0 = by * 64, n0 = bx * 64;

    f32x4 acc[4] = {};

    for (int s = 0; s < DMODEL / 64; ++s) {
        const int k0 = s * 64;
#pragma unroll
        for (int c = 0; c < 2; ++c) {
            const int cc = w * 2 + c;
            gl16(xh + (size_t)(m0 + cc * 8 + srow8) * DMODEL + k0 + le,
                 &Xs[cc * 512]);
            gl16(WT + (size_t)(n0 + cc * 8 + srow8) * DMODEL + k0 + le,
                 &Ws[cc * 512]);
        }
        __syncthreads();
        f16x8 a0 = *(const f16x8*)&Xs[(16 * w + lr) * 64 + swz0];
        f16x8 a1 = *(const f16x8*)&Xs[(16 * w + lr) * 64 + swz1];
#pragma unroll
        for (int nt = 0; nt < 4; ++nt) {
            f16x8 b0 = *(const f16x8*)&Ws[(nt * 16 + lr) * 64 + swz0];
            f16x8 b1 = *(const f16x8*)&Ws[(nt * 16 + lr) * 64 + swz1];
            acc[nt] = MFMA16(a1, b1, MFMA16(a0, b0, acc[nt]));
        }
        __syncthreads();
    }

    const float sc = (bz == 0) ? QSCALE : 1.0f;
    if (bz < 2) {
#pragma unroll
        for (int nt = 0; nt < 4; ++nt)
#pragma unroll
            for (int r = 0; r < 4; ++r)
                Cs[16 * w + lc * 4 + r][nt * 16 + lr] = (f16)(acc[nt][r] * sc);
    } else {
#pragma unroll
        for (int nt = 0; nt < 4; ++nt)
#pragma unroll
            for (int r = 0; r < 4; ++r)
                Cs[nt * 16 + lr][16 * w + lc * 4 + r] = (f16)acc[nt][r];
    }
    __syncthreads();
    {
        const int rr = tid >> 2, cb = (tid & 3) * 16;
        f16x8 v0 = *(const f16x8*)&Cs[rr][cb];
        f16x8 v1 = *(const f16x8*)&Cs[rr][cb + 8];
        f16* dst;
        if (bz == 0)
            dst = q16 + ((size_t)bx * NSEQ + m0 + rr) * DHEAD + cb;
        else if (bz == 1)
            dst = k16 + ((size_t)bx * NSEQ + m0 + rr) * DHEAD + cb;
        else
            dst = vT16 + ((size_t)bx * DHEAD + rr) * NSEQ + m0 + cb;
        *(f16x8*)dst = v0;
        *(f16x8*)(dst + 8) = v1;
    }
}

// ---------------------------------------------------------------------------
// Flash attention, kv-split=2. Block = (qtile 64, head, half); 4 waves, wave
// owns 16 q-rows. Single-buffered K/V/P LDS (24KB) -> 4 blocks/CU = 16
// waves/CU. Swapped QK^T (lane-local softmax), exp2 domain, exact defer-max.
// XCD remap: all blocks of head h -> XCD h (K/V L2-resident per XCD).
// Emits per-split normalized O (f16) + (m,l) partials; combined in out_gemm.
// ---------------------------------------------------------------------------
__global__ __launch_bounds__(256, 4) void attn_fwd(
    const f16* __restrict__ q16, const f16* __restrict__ k16,
    const f16* __restrict__ vT16, f16* __restrict__ Opart,
    float* __restrict__ Ml)
{
    __shared__ __align__(16) f16 Ks[4096];   // [kv 64][d 64] swizzled
    __shared__ __align__(16) f16 Vt[4096];   // [d 64][kv 64] swizzled
    __shared__ __align__(16) f16 Ps[4096];   // [q 64][kv 64] swizzled

    // XCD-aware remap (1024 blocks, 8 XCDs -> head == XCD)
    const int lin = blockIdx.x + 64 * blockIdx.y + 512 * blockIdx.z;
    const int h  = lin & 7;
    const int qb = (lin >> 3) & 63;
    const int sp = lin >> 9;                  // kv half: 0 or 1

    const int tid = threadIdx.x;
    const int w = tid >> 6, lane = tid & 63;
    const int lr = lane & 15, lc = lane >> 4;
    const int srow8 = lane >> 3;
    const int le = 8 * ((lane & 7) ^ srow8);
    const int swz0 = 8 * (lc ^ (lr & 7));
    const int swz1 = 8 * ((lc + 4) ^ (lr & 7));

    const f16* kp = k16 + ((size_t)h * NSEQ + sp * 2048) * DHEAD;
    const f16* vp = vT16 + (size_t)h * DHEAD * NSEQ + sp * 2048;

    // Q fragments (persistent, prescaled by 0.125*log2e)
    const f16* qp = q16 + ((size_t)h * NSEQ + qb * 64 + 16 * w + lr) * DHEAD;
    const f16x8 qf0 = *(const f16x8*)&qp[lc * 8];
    const f16x8 qf1 = *(const f16x8*)&qp[32 + lc * 8];

    float m_run = -INFINITY, l_run = 0.f;
    f32x4 o[4] = {};

    for (int kt = 0; kt < 32; ++kt) {
        // ---- stage K tile and V^T tile (wave w: chunks 2w, 2w+1)
#pragma unroll
        for (int c = 0; c < 2; ++c) {
            const int cc = 2 * w + c;
            gl16(kp + (size_t)(kt * 64 + cc * 8 + srow8) * DHEAD + le,
                 &Ks[cc * 512]);
            gl16(vp + (size_t)(cc * 8 + srow8) * NSEQ + kt * 64 + le,
                 &Vt[cc * 512]);
        }
        __syncthreads();                       // (1) staged (vmcnt drained)

        // ---- S^T = K Q^T: lane holds S[q = lr][kv = 16t + 4lc + r]
        f32x4 sv[4];
        const f32x4 z4 = {0.f, 0.f, 0.f, 0.f};
#pragma unroll
        for (int t = 0; t < 4; ++t) {
            f16x8 ka = *(const f16x8*)&Ks[(t * 16 + lr) * 64 + swz0];
            f16x8 kb = *(const f16x8*)&Ks[(t * 16 + lr) * 64 + swz1];
            sv[t] = MFMA16(kb, qf1, MFMA16(ka, qf0, z4));
        }

        // ---- lane-local online softmax (exp2 domain), exact defer-max
        float pm = sv[0][0];
#pragma unroll
        for (int t = 0; t < 4; ++t)
#pragma unroll
            for (int r = 0; r < 4; ++r) pm = fmaxf(pm, sv[t][r]);
        pm = fmaxf(pm, __shfl_xor(pm, 16));
        pm = fmaxf(pm, __shfl_xor(pm, 32));
        if (__any(pm > m_run)) {
            const float mn = fmaxf(m_run, pm);
            const float al = __builtin_amdgcn_exp2f(m_run - mn);
            m_run = mn;
            l_run *= al;
#pragma unroll
            for (int dt = 0; dt < 4; ++dt) o[dt] *= al;
        }
        float p[4][4];
        float ps = 0.f;
#pragma unroll
        for (int t = 0; t < 4; ++t)
#pragma unroll
            for (int r = 0; r < 4; ++r) {
                p[t][r] = __builtin_amdgcn_exp2f(sv[t][r] - m_run);
                ps += p[t][r];
            }
        ps += __shfl_xor(ps, 16);
        ps += __shfl_xor(ps, 32);
        l_run += ps;

        // ---- P -> LDS (swizzled on elem-group bits [5:3], same as reads)
#pragma unroll
        for (int t = 0; t < 4; ++t) {
            f16x4 pk = {(f16)p[t][0], (f16)p[t][1], (f16)p[t][2], (f16)p[t][3]};
            const int col = (16 * t + 4 * lc) ^ ((lr & 7) << 3);
            *(f16x4*)&Ps[(16 * w + lr) * 64 + col] = pk;
        }

        // ---- O^T += V^T P^T (P read by same wave; lgkmcnt handled)
        f16x8 pb0 = *(const f16x8*)&Ps[(16 * w + lr) * 64 + swz0];
        f16x8 pb1 = *(const f16x8*)&Ps[(16 * w + lr) * 64 + swz1];
#pragma unroll
        for (int dt = 0; dt < 4; ++dt) {
            f16x8 va0 = *(const f16x8*)&Vt[(dt * 16 + lr) * 64 + swz0];
            f16x8 va1 = *(const f16x8*)&Vt[(dt * 16 + lr) * 64 + swz1];
            o[dt] = MFMA16(va1, pb1, MFMA16(va0, pb0, o[dt]));
        }
        __syncthreads();                       // (2) reads done, buffer free
    }

    // ---- epilogue: per-split normalized O (f16) + (m,l)
    const float linv = 1.0f / l_run;
    const size_t qg = (size_t)qb * 64 + 16 * w + lr;
    f16* ob = Opart + (((size_t)(sp * 8 + h)) * NSEQ + qg) * DHEAD;
#pragma unroll
    for (int dt = 0; dt < 4; ++dt) {
        f16x4 ov = {(f16)(o[dt][0] * linv), (f16)(o[dt][1] * linv),
                    (f16)(o[dt][2] * linv), (f16)(o[dt][3] * linv)};
        *(f16x4*)&ob[dt * 16 + 4 * lc] = ov;
    }
    if (lc == 0) {
        float2 ml = make_float2(m_run, l_run);
        *(float2*)&Ml[(((size_t)(sp * 8 + h)) * NSEQ + qg) * 2] = ml;
    }
}

// ---------------------------------------------------------------------------
// Output projection + kv-split combine. K-step s8 == head s8 (INNER = 8*64).
// A-tile staged by combining the two normalized partials with weights from
// (m,l); Ws staged via global_load_lds. f16 MFMA, f32 out + bias.
// ---------------------------------------------------------------------------
__global__ __launch_bounds__(256) void out_gemm16(
    const f16* __restrict__ Opart, const float* __restrict__ Ml,
    const f16* __restrict__ WoT,
    const float* __restrict__ bias, float* __restrict__ C)
{
    __shared__ __align__(16) f16 Xs[4096];
    __shared__ __align__(16) f16 Ws[4096];

    const int bx = blockIdx.x;   // N-tile 0..9
    const int by = blockIdx.y;   // M-tile 0..63
    const int tid = threadIdx.x;
    const int w = tid >> 6, lane = tid & 63;
    const int lr = lane & 15, lc = lane >> 4;
    const int srow8 = lane >> 3;
    const int j = lane & 7;
    const int le = 8 * (j ^ srow8);
    const int swz0 = 8 * (lc ^ (lr & 7));
    const int swz1 = 8 * ((lc + 4) ^ (lr & 7));
    const int m0 = by * 64, n0 = bx * 64;

    f32x4 acc[4] = {};

    for (int s8 = 0; s8 < 8; ++s8) {         // K-step == head
        const int k0 = s8 * 64;
#pragma unroll
        for (int c = 0; c < 2; ++c) {
            const int cc = w * 2 + c;
            // B: WoT via direct-to-LDS
            gl16(WoT + (size_t)(n0 + cc * 8 + srow8) * INNER + k0 + le,
                 &Ws[cc * 512]);
            // A: combine partials in registers, swizzled ds_write
            const int row = cc * 8 + srow8;
            const size_t q = (size_t)m0 + row;
            f16x8 o0 = *(const f16x8*)&Opart[((size_t)s8 * NSEQ + q) * DHEAD + 8 * j];
            f16x8 o1 = *(const f16x8*)&Opart[((size_t)(8 + s8) * NSEQ + q) * DHEAD + 8 * j];
            float2 ml0 = *(const float2*)&Ml[((size_t)s8 * NSEQ + q) * 2];
            float2 ml1 = *(const float2*)&Ml[((size_t)(8 + s8) * NSEQ + q) * 2];
            const float mx = fmaxf(ml0.x, ml1.x);
            float w0 = ml0.y * __builtin_amdgcn_exp2f(ml0.x - mx);
            float w1 = ml1.y * __builtin_amdgcn_exp2f(ml1.x - mx);
            const float inv = 1.0f / (w0 + w1);
            w0 *= inv; w1 *= inv;
            f16x8 a8;
#pragma unroll
            for (int e = 0; e < 8; ++e)
                a8[e] = (f16)((float)o0[e] * w0 + (float)o1[e] * w1);
            *(f16x8*)&Xs[row * 64 + 8 * (j ^ (row & 7))] = a8;
        }
        __syncthreads();
        f16x8 a0 = *(const f16x8*)&Xs[(16 * w + lr) * 64 + swz0];
        f16x8 a1 = *(const f16x8*)&Xs[(16 * w + lr) * 64 + swz1];
#pragma unroll
        for (int nt = 0; nt < 4; ++nt) {
            f16x8 b0 = *(const f16x8*)&Ws[(nt * 16 + lr) * 64 + swz0];
            f16x8 b1 = *(const f16x8*)&Ws[(nt * 16 + lr) * 64 + swz1];
            acc[nt] = MFMA16(a1, b1, MFMA16(a0, b0, acc[nt]));
        }
        __syncthreads();
    }

#pragma unroll
    for (int nt = 0; nt < 4; ++nt) {
        const float b = bias[n0 + nt * 16 + lr];
#pragma unroll
        for (int r = 0; r < 4; ++r)
            C[(size_t)(m0 + 16 * w + lc * 4 + r) * DMODEL + n0 + nt * 16 + lr] =
                acc[nt][r] + b;
    }
}

extern "C" void kernel_launch(void* const* d_in, const int* in_sizes, int n_in,
                              void* d_out, int out_size, void* d_ws, size_t ws_size,
                              hipStream_t stream) {
    const float* x  = (const float*)d_in[0];
    const float* Wq = (const float*)d_in[1];
    const float* Wk = (const float*)d_in[2];
    const float* Wv = (const float*)d_in[3];
    const float* Wo = (const float*)d_in[4];
    const float* bo = (const float*)d_in[5];
    float* out = (float*)d_out;

    // Workspace layout (bytes). Opart overlays xh/WTq/WTk/WTv (lifetimes
    // disjoint: xh/WT die when qkv_gemm16 completes; Opart born in attn).
    char* base = (char*)d_ws;
    f16*   Opart = (f16*)base;                       // [0, 8,388,608)  8 MB
    f16*   xh    = (f16*)base;                       // 4096*640*2 = 5,242,880
    f16*   WTq   = xh + (size_t)NSEQ * DMODEL;       // +655,360
    f16*   WTk   = WTq + (size_t)INNER * DMODEL;
    f16*   WTv   = WTk + (size_t)INNER * DMODEL;     // ends 7,208,960 < 8,388,608
    float* Ml    = (float*)(base + 8388608);         // 131,072 f32 = 524,288 B
    f16*   WoT   = (f16*)(base + 8912896);           // 640*512*2 = 655,360
    f16*   q16   = (f16*)(base + 9568256);           // 8*4096*64*2 = 4,194,304
    f16*   k16   = q16 + (size_t)NHEAD * NSEQ * DHEAD;
    f16*   vT16  = k16 + (size_t)NHEAD * NSEQ * DHEAD;  // ends 22,151,168 B

    cvt_x<<<NSEQ * DMODEL / (256 * 8), 256, 0, stream>>>(x, xh);
    transpose_cvt3<<<dim3(INNER / 64, DMODEL / 64, 3), 256, 0, stream>>>(
        Wq, Wk, Wv, WTq, WTk, WTv);
    transpose_cvt<<<dim3(DMODEL / 64, INNER / 64), 256, 0, stream>>>(
        Wo, WoT, INNER, DMODEL);

    qkv_gemm16<<<dim3(NHEAD, NSEQ / 64, 3), 256, 0, stream>>>(
        xh, WTq, WTk, WTv, q16, k16, vT16);
    attn_fwd<<<dim3(NSEQ / 64, NHEAD, 2), 256, 0, stream>>>(
        q16, k16, vT16, Opart, Ml);
    out_gemm16<<<dim3(DMODEL / 64, NSEQ / 64), 256, 0, stream>>>(
        Opart, Ml, WoT, bo, out);
}